// Round 7
// baseline (353.726 us; speedup 1.0000x reference)
//
#include <hip/hip_runtime.h>
#include <hip/hip_bf16.h>
#include <hip/hip_fp16.h>
#include <math.h>

// ---------------------------------------------------------------------------
// DisplacementTensors: rad = MLP(radial_encode(|r|)) depends only on |r| ->
// tabulate [F(d) | F(d)@w_v | F(d)@w_d] (96 f32/row, 8192 nearest-neighbor
// entries, 3 MB, L2-resident).  CSR segment-sum WITHOUT global atomics:
//   k_hist   : per-block LDS histogram over node tiles -> cnt[b][n]
//   k_colscan: per-node column scan -> basePartial[b][n] (in-place) + tot[n]
//   k_scan   : rowstart = exclusive prefix of tot
//   k_place  : LDS cursor = rowstart+basePartial, LDS-atomic slot, scatter
//              packed 8B payload (f16 rs0,rs1,rs2 | u16 table idx)
//   k_nodes  : one wave per node streams its contiguous slice, branch-free
//              accumulate, direct output writes.
// dtype (bf16 vs f32) detected by probing r_ij halfwords (this dataset: f32).
// Fallback (small ws): global-atomic rank path.
// ---------------------------------------------------------------------------

#define TSIZE 8192
#define DMAX  2.0f           // RBF centers <=1, width 1/8 -> F const beyond ~2
#define NPB   4              // nodes (waves) per block in k_nodes
#define EPB   4              // entries per block in k_table
#define HB    32             // histogram blocks
#define TILE  10240          // node-tile size (40 KB LDS)

// f32 concat-weight offsets (floats)
#define O_WRAD 0
#define O_BRAD 256
#define O_WDIR 288
#define O_W1   1312
#define O_B1   3360
#define O_W2   3424
#define O_B2   7520
#define O_W3   7584
#define O_B3   9632
#define O_WV   9664
#define O_WD   10688
#define W_TOT  11712

__device__ __forceinline__ float lrelu(float x) { return x > 0.0f ? x : 0.1f * x; }

__device__ __forceinline__ float ldf(const void* p, int i, bool f32) {
    return f32 ? ((const float*)p)[i]
               : __uint_as_float(((unsigned int)((const unsigned short*)p)[i]) << 16);
}
__device__ __forceinline__ void stf(void* p, size_t i, float v, bool f32) {
    if (f32) ((float*)p)[i] = v;
    else     ((__hip_bfloat16*)p)[i] = __float2bfloat16(v);
}

// probe first 128 halfwords of r_ij as bf16: f32 data's low halves have random
// exponents -> non-finite/huge values appear with P ~ 1-1e-16.
__device__ __forceinline__ bool detect_f32(const void* r) {
    const unsigned short* p = (const unsigned short*)r;
    int bad = 0;
#pragma unroll 8
    for (int i = 0; i < 128; i++) {
        float v = __uint_as_float(((unsigned int)p[i]) << 16);
        bad |= (!isfinite(v) || fabsf(v) > 1e5f) ? 1 : 0;
    }
    return bad != 0;
}

// --- prep: flag store | weight->f32 concat | (fallback) zero counts --------
__global__ void k_prep(const void* __restrict__ r_ij,
                       const void* w_rad, const void* b_rad, const void* w_direct,
                       const void* w1, const void* b1, const void* w2, const void* b2,
                       const void* w3, const void* b3, const void* w_v, const void* w_d,
                       float* __restrict__ wcat, int* __restrict__ flag,
                       int* __restrict__ counts, int N) {
    const int b = blockIdx.x;
    if (b == 0) {
        if (threadIdx.x == 0) flag[0] = detect_f32(r_ij) ? 1 : 0;
    } else if (b <= 11) {
        const bool f32 = detect_f32(r_ij);
        const void* src; int cnt; int off;
        switch (b) {
            case 1:  src = w_rad;    cnt = 256;  off = O_WRAD; break;
            case 2:  src = b_rad;    cnt = 32;   off = O_BRAD; break;
            case 3:  src = w_direct; cnt = 1024; off = O_WDIR; break;
            case 4:  src = w1;       cnt = 2048; off = O_W1;   break;
            case 5:  src = b1;       cnt = 64;   off = O_B1;   break;
            case 6:  src = w2;       cnt = 4096; off = O_W2;   break;
            case 7:  src = b2;       cnt = 64;   off = O_B2;   break;
            case 8:  src = w3;       cnt = 2048; off = O_W3;   break;
            case 9:  src = b3;       cnt = 32;   off = O_B3;   break;
            case 10: src = w_v;      cnt = 1024; off = O_WV;   break;
            default: src = w_d;      cnt = 1024; off = O_WD;   break;
        }
        for (int i = threadIdx.x; i < cnt; i += blockDim.x)
            wcat[off + i] = ldf(src, i, f32);
    } else if (counts) {
        int i = (b - 12) * blockDim.x + threadIdx.x;
        if (i < N) counts[i] = 0;
    }
}

// --- LUT build: 4 entries/block, wave = entry, lane = neuron ---------------
__global__ void __launch_bounds__(64 * EPB) k_table(const float* __restrict__ wcat,
                                                    float* __restrict__ tabI) {
    __shared__ float Lh[EPB][32], Lt1[EPB][64], Lt2[EPB][64], Lrad[EPB][32];

    const int s = threadIdx.x >> 6;          // entry slot (== wave id)
    const int j = threadIdx.x & 63;          // neuron
    const int e = blockIdx.x * EPB + s;
    const float d = (float)e * (DMAX / (float)(TSIZE - 1));

    float enc[8];
#pragma unroll
    for (int k = 0; k < 8; k++) {
        float t = (d - (float)k * (1.0f / 7.0f)) * 8.0f;
        enc[k] = expf(-t * t);
    }

    if (j < 32) {                            // h = enc @ w_rad + b_rad
        float hv = wcat[O_BRAD + j];
#pragma unroll
        for (int k = 0; k < 8; k++) hv = fmaf(enc[k], wcat[O_WRAD + k * 32 + j], hv);
        Lh[s][j] = hv;
    }
    __syncthreads();

    {                                        // t1 = lrelu(h @ w1 + b1)
        float v = wcat[O_B1 + j];
#pragma unroll
        for (int i = 0; i < 32; i++) v = fmaf(Lh[s][i], wcat[O_W1 + i * 64 + j], v);
        Lt1[s][j] = lrelu(v);
    }
    __syncthreads();

    {                                        // t2 = lrelu(t1 @ w2 + b2)
        float v = wcat[O_B2 + j];
#pragma unroll
        for (int i = 0; i < 64; i++) v = fmaf(Lt1[s][i], wcat[O_W2 + i * 64 + j], v);
        Lt2[s][j] = lrelu(v);
    }
    __syncthreads();

    if (j < 32) {                            // rad = h@w_direct + t2@w3 + b3
        float v = wcat[O_B3 + j];
#pragma unroll
        for (int i = 0; i < 64; i++) v = fmaf(Lt2[s][i], wcat[O_W3 + i * 32 + j], v);
#pragma unroll
        for (int i = 0; i < 32; i++) v = fmaf(Lh[s][i], wcat[O_WDIR + i * 32 + j], v);
        Lrad[s][j] = v;
        tabI[e * 96 + j] = v;
    }
    __syncthreads();

    if (j < 32) {                            // folded output transforms
        float sv = 0.0f, sd = 0.0f;
#pragma unroll
        for (int i = 0; i < 32; i++) {
            float ri = Lrad[s][i];
            sv = fmaf(ri, wcat[O_WV + i * 32 + j], sv);
            sd = fmaf(ri, wcat[O_WD + i * 32 + j], sd);
        }
        tabI[e * 96 + 32 + j] = sv;
        tabI[e * 96 + 64 + j] = sd;
    }
}

// --- LDS-histogram CSR build (no global atomics) ---------------------------
__global__ void __launch_bounds__(256) k_hist(const int* __restrict__ src, int E,
                                              int chunk, int* __restrict__ cnt,
                                              int N) {
    __shared__ int lcnt[TILE];
    const int b = blockIdx.x;
    const int lo = b * chunk;
    const int hi = min(lo + chunk, E);
    const int ntiles = (N + TILE - 1) / TILE;

    for (int t = 0; t < ntiles; t++) {
        const int t0 = t * TILE;
        const int tl = min(TILE, N - t0);
        for (int i = threadIdx.x; i < tl; i += 256) lcnt[i] = 0;
        __syncthreads();
        for (int e = lo + threadIdx.x; e < hi; e += 256) {
            const int s = src[e] - t0;
            if ((unsigned)s < (unsigned)tl) atomicAdd(&lcnt[s], 1);
        }
        __syncthreads();
        for (int i = threadIdx.x; i < tl; i += 256)
            cnt[b * N + t0 + i] = lcnt[i];
        __syncthreads();
    }
}

// column scan: basePartial[b][n] (in place) + tot[n]
__global__ void k_colscan(int* __restrict__ cnt, int* __restrict__ tot, int N) {
    int n = blockIdx.x * blockDim.x + threadIdx.x;
    if (n >= N) return;
    int run = 0;
#pragma unroll 4
    for (int b = 0; b < HB; b++) {
        int c = cnt[b * N + n];
        cnt[b * N + n] = run;
        run += c;
    }
    tot[n] = run;
}

__global__ void k_scan(const int* __restrict__ tot, int* __restrict__ rowstart,
                       int N, int E) {
    __shared__ int part[1024];
    const int t = threadIdx.x;
    const int CH = (N + 1023) / 1024;
    const int lo = t * CH;
    const int hi = min(lo + CH, N);

    int s = 0;
    for (int i = lo; i < hi; i++) s += tot[i];
    part[t] = s;
    __syncthreads();

    for (int off = 1; off < 1024; off <<= 1) {
        int v = part[t];
        int w = (t >= off) ? part[t - off] : 0;
        __syncthreads();
        part[t] = v + w;
        __syncthreads();
    }

    int run = (t == 0) ? 0 : part[t - 1];
    for (int i = lo; i < hi; i++) {
        rowstart[i] = run;
        run += tot[i];
    }
    if (t == 0) rowstart[N] = E;
}

// place payload via LDS cursor (rowstart + basePartial), LDS-atomic slot
__global__ void __launch_bounds__(256) k_place(
        const int* __restrict__ src, int E, int chunk,
        const int* __restrict__ cnt, const int* __restrict__ rowstart,
        const void* __restrict__ r_ij, const int* __restrict__ flag,
        uint2* __restrict__ eps, int N) {
    __shared__ int cur[TILE];
    const int b = blockIdx.x;
    const int lo = b * chunk;
    const int hi = min(lo + chunk, E);
    const int ntiles = (N + TILE - 1) / TILE;
    const bool f32 = flag[0] != 0;

    for (int t = 0; t < ntiles; t++) {
        const int t0 = t * TILE;
        const int tl = min(TILE, N - t0);
        for (int i = threadIdx.x; i < tl; i += 256)
            cur[i] = rowstart[t0 + i] + cnt[b * N + t0 + i];
        __syncthreads();
        for (int e = lo + threadIdx.x; e < hi; e += 256) {
            const int s = src[e] - t0;
            if ((unsigned)s < (unsigned)tl) {
                const int pos = atomicAdd(&cur[s], 1);
                const float x = ldf(r_ij, 3 * e + 0, f32);
                const float y = ldf(r_ij, 3 * e + 1, f32);
                const float z = ldf(r_ij, 3 * e + 2, f32);
                const float d2 = x * x + y * y + z * z;
                const float inv = rsqrtf(1.0f + 49.0f * d2);  // tens_sigmoid(7r)
                const float u = fminf(sqrtf(d2), DMAX) * ((float)(TSIZE - 1) / DMAX);
                const unsigned int ti = (unsigned int)(u + 0.5f);
                const unsigned int h0 = __half_as_ushort(__float2half(7.0f * x * inv));
                const unsigned int h1 = __half_as_ushort(__float2half(7.0f * y * inv));
                const unsigned int h2 = __half_as_ushort(__float2half(7.0f * z * inv));
                eps[pos] = make_uint2(h0 | (h1 << 16), h2 | (ti << 16));
            }
        }
        __syncthreads();
    }
}

// --- fallback CSR (global atomics), used only when ws too small ------------
__global__ void k_rank_g(const int* __restrict__ src, int* __restrict__ counts,
                         int* __restrict__ rank, int E) {
    int e = blockIdx.x * blockDim.x + threadIdx.x;
    if (e < E) rank[e] = atomicAdd(&counts[src[e]], 1);
}
__global__ void k_place_g(const int* __restrict__ src, const int* __restrict__ rank,
                          const int* __restrict__ rowstart,
                          int* __restrict__ perm, int E) {
    int e = blockIdx.x * blockDim.x + threadIdx.x;
    if (e < E) perm[rowstart[src[e]] + rank[e]] = e;
}

// --- per-node accumulation: one wave per node, branch-free -----------------
// lane = (a = lane&31) x (half = lane>>5).
// b1 = (half? rd : rv)*(half? rs1 : 1);  b2 = rd*(half? rs2 : rs0).
__global__ void __launch_bounds__(64 * NPB) k_nodes(
    const uint2* __restrict__ eps,
    const int* __restrict__ perm,
    const void* __restrict__ r_ij,
    const int* __restrict__ rowstart,
    const float* __restrict__ tabI,
    const int* __restrict__ flag,
    void* __restrict__ out, int N) {
    const int wave = threadIdx.x >> 6;
    const int lane = threadIdx.x & 63;
    const int n = blockIdx.x * NPB + wave;
    if (n >= N) return;
    const int a = lane & 31;
    const bool hi = (lane >> 5) != 0;
    const bool f32 = flag[0] != 0;

    const int s0 = rowstart[n];
    const int s1 = rowstart[n + 1];

    float accR = 0.f, acc1 = 0.f, acc2 = 0.f, acc3 = 0.f,
          acc4 = 0.f, acc5 = 0.f, acc6 = 0.f;

    if (eps) {
        int idx = s0;
        for (; idx + 1 < s1; idx += 2) {          // unroll x2: overlap loads
            const uint2 qa = eps[idx];
            const uint2 qb = eps[idx + 1];
            const float ax = __half2float(__ushort_as_half((unsigned short)(qa.x & 0xffff)));
            const float ay = __half2float(__ushort_as_half((unsigned short)(qa.x >> 16)));
            const float az = __half2float(__ushort_as_half((unsigned short)(qa.y & 0xffff)));
            const int   ab = (int)(qa.y >> 16) * 96 + a;
            const float bx = __half2float(__ushort_as_half((unsigned short)(qb.x & 0xffff)));
            const float by = __half2float(__ushort_as_half((unsigned short)(qb.x >> 16)));
            const float bz = __half2float(__ushort_as_half((unsigned short)(qb.y & 0xffff)));
            const int   bb = (int)(qb.y >> 16) * 96 + a;

            const float raA = tabI[ab], rvA = tabI[ab + 32], rdA = tabI[ab + 64];
            const float raB = tabI[bb], rvB = tabI[bb + 32], rdB = tabI[bb + 64];

            const float b1A = (hi ? rdA : rvA) * (hi ? ay : 1.0f);
            const float b2A = rdA * (hi ? az : ax);
            const float b1B = (hi ? rdB : rvB) * (hi ? by : 1.0f);
            const float b2B = rdB * (hi ? bz : bx);

            accR += raA + raB;
            acc1 += b1A * ax + b1B * bx;
            acc2 += b1A * ay + b1B * by;
            acc3 += b1A * az + b1B * bz;
            acc4 += b2A * ax + b2B * bx;
            acc5 += b2A * ay + b2B * by;
            acc6 += b2A * az + b2B * bz;
        }
        if (idx < s1) {
            const uint2 q = eps[idx];
            const float x = __half2float(__ushort_as_half((unsigned short)(q.x & 0xffff)));
            const float y = __half2float(__ushort_as_half((unsigned short)(q.x >> 16)));
            const float z = __half2float(__ushort_as_half((unsigned short)(q.y & 0xffff)));
            const int   b = (int)(q.y >> 16) * 96 + a;
            const float ra = tabI[b], rv = tabI[b + 32], rd = tabI[b + 64];
            const float b1 = (hi ? rd : rv) * (hi ? y : 1.0f);
            const float b2 = rd * (hi ? z : x);
            accR += ra;
            acc1 += b1 * x; acc2 += b1 * y; acc3 += b1 * z;
            acc4 += b2 * x; acc5 += b2 * y; acc6 += b2 * z;
        }
    } else {
        for (int idx = s0; idx < s1; idx++) {
            const int e = perm[idx];
            const float x0 = ldf(r_ij, 3 * e + 0, f32);
            const float y0 = ldf(r_ij, 3 * e + 1, f32);
            const float z0 = ldf(r_ij, 3 * e + 2, f32);
            const float d2 = x0 * x0 + y0 * y0 + z0 * z0;
            const float inv = rsqrtf(1.0f + 49.0f * d2);
            const float x = 7.0f * x0 * inv, y = 7.0f * y0 * inv, z = 7.0f * z0 * inv;
            const float u = fminf(sqrtf(d2), DMAX) * ((float)(TSIZE - 1) / DMAX);
            const int b = (int)(u + 0.5f) * 96 + a;
            const float ra = tabI[b], rv = tabI[b + 32], rd = tabI[b + 64];
            const float b1 = (hi ? rd : rv) * (hi ? y : 1.0f);
            const float b2 = rd * (hi ? z : x);
            accR += ra;
            acc1 += b1 * x; acc2 += b1 * y; acc3 += b1 * z;
            acc4 += b2 * x; acc5 += b2 * y; acc6 += b2 * z;
        }
    }

    const size_t baseV = (size_t)N * 32;
    const size_t baseD = (size_t)N * 128;
    if (!hi) {
        stf(out, (size_t)n * 32 + a, accR, f32);
        const size_t vb = baseV + (size_t)n * 96 + a * 3;
        stf(out, vb + 0, acc1, f32);
        stf(out, vb + 1, acc2, f32);
        stf(out, vb + 2, acc3, f32);
        const size_t db = baseD + (size_t)n * 288 + a * 9;
        stf(out, db + 0, acc4, f32);
        stf(out, db + 1, acc5, f32);
        stf(out, db + 2, acc6, f32);
    } else {
        const size_t db = baseD + (size_t)n * 288 + a * 9;
        stf(out, db + 3, acc1, f32);
        stf(out, db + 4, acc2, f32);
        stf(out, db + 5, acc3, f32);
        stf(out, db + 6, acc4, f32);
        stf(out, db + 7, acc5, f32);
        stf(out, db + 8, acc6, f32);
    }
}

extern "C" void kernel_launch(void* const* d_in, const int* in_sizes, int n_in,
                              void* d_out, int out_size, void* d_ws, size_t ws_size,
                              hipStream_t stream) {
    const void* r_ij     = d_in[0];
    const void* w_rad    = d_in[1];
    const void* b_rad    = d_in[2];
    const void* w_direct = d_in[3];
    const void* w1       = d_in[4];
    const void* b1       = d_in[5];
    const void* w2       = d_in[6];
    const void* b2       = d_in[7];
    const void* w3       = d_in[8];
    const void* b3       = d_in[9];
    const void* w_v      = d_in[10];
    const void* w_d      = d_in[11];
    const int* edges_src = (const int*)d_in[12];

    const int E = in_sizes[12];
    const int N = out_size / 416;   // 32 + 96 + 288 per node
    const int chunk = (E + HB - 1) / HB;

    // fast-path layout: eps | wcat | flag | tabI | cnt[HB][N] | tot | rowstart
    const size_t fastBytes = (size_t)E * 8
                           + ((size_t)W_TOT + 4 + (size_t)TSIZE * 96
                              + (size_t)HB * N + (size_t)N + (size_t)(N + 1)) * 4;
    const bool use_fast = ws_size >= fastBytes + 64;

    char* w = (char*)d_ws;
    if (use_fast) {
        uint2* eps    = (uint2*)w;
        float* wcat   = (float*)(w + (size_t)E * 8);
        int* flag     = (int*)(wcat + W_TOT);
        float* tabI   = (float*)(flag + 4);
        int* cnt      = (int*)(tabI + (size_t)TSIZE * 96);
        int* tot      = cnt + (size_t)HB * N;
        int* rowstart = tot + N;              // N+1

        k_prep<<<12, 256, 0, stream>>>(
            r_ij, w_rad, b_rad, w_direct, w1, b1, w2, b2, w3, b3, w_v, w_d,
            wcat, flag, nullptr, N);
        k_table<<<TSIZE / EPB, 64 * EPB, 0, stream>>>(wcat, tabI);
        k_hist<<<HB, 256, 0, stream>>>(edges_src, E, chunk, cnt, N);
        k_colscan<<<(N + 255) / 256, 256, 0, stream>>>(cnt, tot, N);
        k_scan<<<1, 1024, 0, stream>>>(tot, rowstart, N, E);
        k_place<<<HB, 256, 0, stream>>>(edges_src, E, chunk, cnt, rowstart,
                                        r_ij, flag, eps, N);
        k_nodes<<<(N + NPB - 1) / NPB, 64 * NPB, 0, stream>>>(
            eps, nullptr, r_ij, rowstart, tabI, flag, d_out, N);
    } else {
        // fallback: global-atomic rank path, perm-indexed k_nodes
        int* perm     = (int*)w;              // E
        float* wcat   = (float*)(w + (size_t)E * 4);
        int* flag     = (int*)(wcat + W_TOT);
        float* tabI   = (float*)(flag + 4);
        int* counts   = (int*)(tabI + (size_t)TSIZE * 96);
        int* rowstart = counts + N;           // N+1
        int* rank     = rowstart + N + 1;     // E

        k_prep<<<12 + (N + 255) / 256, 256, 0, stream>>>(
            r_ij, w_rad, b_rad, w_direct, w1, b1, w2, b2, w3, b3, w_v, w_d,
            wcat, flag, counts, N);
        k_table<<<TSIZE / EPB, 64 * EPB, 0, stream>>>(wcat, tabI);
        k_rank_g<<<(E + 255) / 256, 256, 0, stream>>>(edges_src, counts, rank, E);
        k_scan<<<1, 1024, 0, stream>>>(counts, rowstart, N, E);
        k_place_g<<<(E + 255) / 256, 256, 0, stream>>>(edges_src, rank, rowstart,
                                                       perm, E);
        k_nodes<<<(N + NPB - 1) / NPB, 64 * NPB, 0, stream>>>(
            nullptr, perm, r_ij, rowstart, tabI, flag, d_out, N);
    }
}

// Round 8
// 232.406 us; speedup vs baseline: 1.5220x; 1.5220x over previous
//
#include <hip/hip_runtime.h>
#include <hip/hip_bf16.h>
#include <hip/hip_fp16.h>
#include <math.h>

// ---------------------------------------------------------------------------
// DisplacementTensors: rad = MLP(radial_encode(|r|)) depends only on |r| ->
// tabulate [F(d) | F(d)@w_v | F(d)@w_d] (96 f32/row, 8192 nearest-neighbor
// entries, 3 MB, L2-resident).  CSR segment-sum WITHOUT global atomics,
// grid = (edge-chunk x node-tile) so all 256 CUs stay busy (R7 used 32
// blocks -> 1.3% occupancy; that was the failure):
//   k_hist   : 128 chunks x 2 tiles; LDS histogram -> u16 cnt[t][b][nl]
//   k_colscan: per-node scan over chunks -> cnt := exclusive prefix, tot[n]
//   k_scan   : rowstart = exclusive prefix of tot
//   k_place  : same grid; LDS cursor = rowstart+cnt, LDS-atomic slot,
//              scatter packed 8B payload (f16 rs0,rs1,rs2 | u16 table idx)
//   k_nodes  : one wave per node streams its contiguous slice, branch-free
//              accumulate, direct output writes.  (unchanged, 55 us @ R6)
// dtype (bf16 vs f32) detected by probing r_ij halfwords (this dataset: f32).
// Fallback (small ws): R6 global-atomic rank path.
// ---------------------------------------------------------------------------

#define TSIZE 8192
#define DMAX  2.0f           // RBF centers <=1, width 1/8 -> F const beyond ~2
#define NPB   4              // nodes (waves) per block in k_nodes
#define EPB   4              // entries per block in k_table
#define HB    128            // edge chunks (hist/place blocks per node tile)
#define TILE  10240          // node-tile size (40 KB LDS)

// f32 concat-weight offsets (floats)
#define O_WRAD 0
#define O_BRAD 256
#define O_WDIR 288
#define O_W1   1312
#define O_B1   3360
#define O_W2   3424
#define O_B2   7520
#define O_W3   7584
#define O_B3   9632
#define O_WV   9664
#define O_WD   10688
#define W_TOT  11712

__device__ __forceinline__ float lrelu(float x) { return x > 0.0f ? x : 0.1f * x; }

__device__ __forceinline__ float ldf(const void* p, int i, bool f32) {
    return f32 ? ((const float*)p)[i]
               : __uint_as_float(((unsigned int)((const unsigned short*)p)[i]) << 16);
}
__device__ __forceinline__ void stf(void* p, size_t i, float v, bool f32) {
    if (f32) ((float*)p)[i] = v;
    else     ((__hip_bfloat16*)p)[i] = __float2bfloat16(v);
}

// probe first 128 halfwords of r_ij as bf16: f32 data's low halves have random
// exponents -> non-finite/huge values appear with P ~ 1-1e-16.
__device__ __forceinline__ bool detect_f32(const void* r) {
    const unsigned short* p = (const unsigned short*)r;
    int bad = 0;
#pragma unroll 8
    for (int i = 0; i < 128; i++) {
        float v = __uint_as_float(((unsigned int)p[i]) << 16);
        bad |= (!isfinite(v) || fabsf(v) > 1e5f) ? 1 : 0;
    }
    return bad != 0;
}

// --- prep: flag store | weight->f32 concat | (fallback) zero counts --------
__global__ void k_prep(const void* __restrict__ r_ij,
                       const void* w_rad, const void* b_rad, const void* w_direct,
                       const void* w1, const void* b1, const void* w2, const void* b2,
                       const void* w3, const void* b3, const void* w_v, const void* w_d,
                       float* __restrict__ wcat, int* __restrict__ flag,
                       int* __restrict__ counts, int N) {
    const int b = blockIdx.x;
    if (b == 0) {
        if (threadIdx.x == 0) flag[0] = detect_f32(r_ij) ? 1 : 0;
    } else if (b <= 11) {
        const bool f32 = detect_f32(r_ij);
        const void* src; int cnt; int off;
        switch (b) {
            case 1:  src = w_rad;    cnt = 256;  off = O_WRAD; break;
            case 2:  src = b_rad;    cnt = 32;   off = O_BRAD; break;
            case 3:  src = w_direct; cnt = 1024; off = O_WDIR; break;
            case 4:  src = w1;       cnt = 2048; off = O_W1;   break;
            case 5:  src = b1;       cnt = 64;   off = O_B1;   break;
            case 6:  src = w2;       cnt = 4096; off = O_W2;   break;
            case 7:  src = b2;       cnt = 64;   off = O_B2;   break;
            case 8:  src = w3;       cnt = 2048; off = O_W3;   break;
            case 9:  src = b3;       cnt = 32;   off = O_B3;   break;
            case 10: src = w_v;      cnt = 1024; off = O_WV;   break;
            default: src = w_d;      cnt = 1024; off = O_WD;   break;
        }
        for (int i = threadIdx.x; i < cnt; i += blockDim.x)
            wcat[off + i] = ldf(src, i, f32);
    } else if (counts) {
        int i = (b - 12) * blockDim.x + threadIdx.x;
        if (i < N) counts[i] = 0;
    }
}

// --- LUT build: 4 entries/block, wave = entry, lane = neuron ---------------
__global__ void __launch_bounds__(64 * EPB) k_table(const float* __restrict__ wcat,
                                                    float* __restrict__ tabI) {
    __shared__ float Lh[EPB][32], Lt1[EPB][64], Lt2[EPB][64], Lrad[EPB][32];

    const int s = threadIdx.x >> 6;          // entry slot (== wave id)
    const int j = threadIdx.x & 63;          // neuron
    const int e = blockIdx.x * EPB + s;
    const float d = (float)e * (DMAX / (float)(TSIZE - 1));

    float enc[8];
#pragma unroll
    for (int k = 0; k < 8; k++) {
        float t = (d - (float)k * (1.0f / 7.0f)) * 8.0f;
        enc[k] = expf(-t * t);
    }

    if (j < 32) {                            // h = enc @ w_rad + b_rad
        float hv = wcat[O_BRAD + j];
#pragma unroll
        for (int k = 0; k < 8; k++) hv = fmaf(enc[k], wcat[O_WRAD + k * 32 + j], hv);
        Lh[s][j] = hv;
    }
    __syncthreads();

    {                                        // t1 = lrelu(h @ w1 + b1)
        float v = wcat[O_B1 + j];
#pragma unroll
        for (int i = 0; i < 32; i++) v = fmaf(Lh[s][i], wcat[O_W1 + i * 64 + j], v);
        Lt1[s][j] = lrelu(v);
    }
    __syncthreads();

    {                                        // t2 = lrelu(t1 @ w2 + b2)
        float v = wcat[O_B2 + j];
#pragma unroll
        for (int i = 0; i < 64; i++) v = fmaf(Lt1[s][i], wcat[O_W2 + i * 64 + j], v);
        Lt2[s][j] = lrelu(v);
    }
    __syncthreads();

    if (j < 32) {                            // rad = h@w_direct + t2@w3 + b3
        float v = wcat[O_B3 + j];
#pragma unroll
        for (int i = 0; i < 64; i++) v = fmaf(Lt2[s][i], wcat[O_W3 + i * 32 + j], v);
#pragma unroll
        for (int i = 0; i < 32; i++) v = fmaf(Lh[s][i], wcat[O_WDIR + i * 32 + j], v);
        Lrad[s][j] = v;
        tabI[e * 96 + j] = v;
    }
    __syncthreads();

    if (j < 32) {                            // folded output transforms
        float sv = 0.0f, sd = 0.0f;
#pragma unroll
        for (int i = 0; i < 32; i++) {
            float ri = Lrad[s][i];
            sv = fmaf(ri, wcat[O_WV + i * 32 + j], sv);
            sd = fmaf(ri, wcat[O_WD + i * 32 + j], sd);
        }
        tabI[e * 96 + 32 + j] = sv;
        tabI[e * 96 + 64 + j] = sd;
    }
}

// --- CSR build, pass 1: per-(chunk,tile) LDS histogram -> u16 cnt ----------
// grid: HB * ntiles blocks; b = chunk, t = tile.
__global__ void __launch_bounds__(256) k_hist(const int* __restrict__ src, int E,
                                              int chunk,
                                              unsigned short* __restrict__ cnt,
                                              int N) {
    __shared__ int lcnt[TILE];
    const int b = blockIdx.x % HB;
    const int t = blockIdx.x / HB;
    const int lo = b * chunk;
    const int hi = min(lo + chunk, E);
    const int t0 = t * TILE;
    const int tl = min(TILE, N - t0);

    for (int i = threadIdx.x; i < tl; i += 256) lcnt[i] = 0;
    __syncthreads();
    for (int e = lo + threadIdx.x; e < hi; e += 256) {
        const int s = src[e] - t0;
        if ((unsigned)s < (unsigned)tl) atomicAdd(&lcnt[s], 1);
    }
    __syncthreads();
    unsigned short* out = cnt + (size_t)(t * HB + b) * TILE;
    for (int i = threadIdx.x; i < tl; i += 256)
        out[i] = (unsigned short)lcnt[i];
}

// pass 2: per-node scan over chunks; cnt := exclusive prefix, tot[n] = sum
__global__ void k_colscan(unsigned short* __restrict__ cnt,
                          int* __restrict__ tot, int N) {
    int n = blockIdx.x * blockDim.x + threadIdx.x;
    if (n >= N) return;
    const int t = n / TILE;
    const int nl = n % TILE;
    unsigned short* col = cnt + (size_t)(t * HB) * TILE + nl;
    int run = 0;
#pragma unroll 4
    for (int b = 0; b < HB; b++) {
        int c = col[(size_t)b * TILE];
        col[(size_t)b * TILE] = (unsigned short)run;
        run += c;
    }
    tot[n] = run;
}

__global__ void k_scan(const int* __restrict__ tot, int* __restrict__ rowstart,
                       int N, int E) {
    __shared__ int part[1024];
    const int t = threadIdx.x;
    const int CH = (N + 1023) / 1024;
    const int lo = t * CH;
    const int hi = min(lo + CH, N);

    int s = 0;
    for (int i = lo; i < hi; i++) s += tot[i];
    part[t] = s;
    __syncthreads();

    for (int off = 1; off < 1024; off <<= 1) {
        int v = part[t];
        int w = (t >= off) ? part[t - off] : 0;
        __syncthreads();
        part[t] = v + w;
        __syncthreads();
    }

    int run = (t == 0) ? 0 : part[t - 1];
    for (int i = lo; i < hi; i++) {
        rowstart[i] = run;
        run += tot[i];
    }
    if (t == 0) rowstart[N] = E;
}

// pass 3: place payload via LDS cursor (rowstart + cnt prefix), LDS atomics
__global__ void __launch_bounds__(256) k_place(
        const int* __restrict__ src, int E, int chunk,
        const unsigned short* __restrict__ cnt, const int* __restrict__ rowstart,
        const void* __restrict__ r_ij, const int* __restrict__ flag,
        uint2* __restrict__ eps, int N) {
    __shared__ int cur[TILE];
    const int b = blockIdx.x % HB;
    const int t = blockIdx.x / HB;
    const int lo = b * chunk;
    const int hi = min(lo + chunk, E);
    const int t0 = t * TILE;
    const int tl = min(TILE, N - t0);
    const bool f32 = flag[0] != 0;

    const unsigned short* base = cnt + (size_t)(t * HB + b) * TILE;
    for (int i = threadIdx.x; i < tl; i += 256)
        cur[i] = rowstart[t0 + i] + (int)base[i];
    __syncthreads();
    for (int e = lo + threadIdx.x; e < hi; e += 256) {
        const int s = src[e] - t0;
        if ((unsigned)s < (unsigned)tl) {
            const int pos = atomicAdd(&cur[s], 1);
            const float x = ldf(r_ij, 3 * e + 0, f32);
            const float y = ldf(r_ij, 3 * e + 1, f32);
            const float z = ldf(r_ij, 3 * e + 2, f32);
            const float d2 = x * x + y * y + z * z;
            const float inv = rsqrtf(1.0f + 49.0f * d2);  // tens_sigmoid(7r)
            const float u = fminf(sqrtf(d2), DMAX) * ((float)(TSIZE - 1) / DMAX);
            const unsigned int ti = (unsigned int)(u + 0.5f);
            const unsigned int h0 = __half_as_ushort(__float2half(7.0f * x * inv));
            const unsigned int h1 = __half_as_ushort(__float2half(7.0f * y * inv));
            const unsigned int h2 = __half_as_ushort(__float2half(7.0f * z * inv));
            eps[pos] = make_uint2(h0 | (h1 << 16), h2 | (ti << 16));
        }
    }
}

// --- fallback CSR (global atomics), used only when ws too small ------------
__global__ void k_rank_g(const int* __restrict__ src, int* __restrict__ counts,
                         int* __restrict__ rank, int E) {
    int e = blockIdx.x * blockDim.x + threadIdx.x;
    if (e < E) rank[e] = atomicAdd(&counts[src[e]], 1);
}
__global__ void k_place_g(const int* __restrict__ src, const int* __restrict__ rank,
                          const int* __restrict__ rowstart,
                          int* __restrict__ perm, int E) {
    int e = blockIdx.x * blockDim.x + threadIdx.x;
    if (e < E) perm[rowstart[src[e]] + rank[e]] = e;
}

// --- per-node accumulation: one wave per node, branch-free -----------------
// lane = (a = lane&31) x (half = lane>>5).
// b1 = (half? rd : rv)*(half? rs1 : 1);  b2 = rd*(half? rs2 : rs0).
__global__ void __launch_bounds__(64 * NPB) k_nodes(
    const uint2* __restrict__ eps,
    const int* __restrict__ perm,
    const void* __restrict__ r_ij,
    const int* __restrict__ rowstart,
    const float* __restrict__ tabI,
    const int* __restrict__ flag,
    void* __restrict__ out, int N) {
    const int wave = threadIdx.x >> 6;
    const int lane = threadIdx.x & 63;
    const int n = blockIdx.x * NPB + wave;
    if (n >= N) return;
    const int a = lane & 31;
    const bool hi = (lane >> 5) != 0;
    const bool f32 = flag[0] != 0;

    const int s0 = rowstart[n];
    const int s1 = rowstart[n + 1];

    float accR = 0.f, acc1 = 0.f, acc2 = 0.f, acc3 = 0.f,
          acc4 = 0.f, acc5 = 0.f, acc6 = 0.f;

    if (eps) {
        int idx = s0;
        for (; idx + 1 < s1; idx += 2) {          // unroll x2: overlap loads
            const uint2 qa = eps[idx];
            const uint2 qb = eps[idx + 1];
            const float ax = __half2float(__ushort_as_half((unsigned short)(qa.x & 0xffff)));
            const float ay = __half2float(__ushort_as_half((unsigned short)(qa.x >> 16)));
            const float az = __half2float(__ushort_as_half((unsigned short)(qa.y & 0xffff)));
            const int   ab = (int)(qa.y >> 16) * 96 + a;
            const float bx = __half2float(__ushort_as_half((unsigned short)(qb.x & 0xffff)));
            const float by = __half2float(__ushort_as_half((unsigned short)(qb.x >> 16)));
            const float bz = __half2float(__ushort_as_half((unsigned short)(qb.y & 0xffff)));
            const int   bb = (int)(qb.y >> 16) * 96 + a;

            const float raA = tabI[ab], rvA = tabI[ab + 32], rdA = tabI[ab + 64];
            const float raB = tabI[bb], rvB = tabI[bb + 32], rdB = tabI[bb + 64];

            const float b1A = (hi ? rdA : rvA) * (hi ? ay : 1.0f);
            const float b2A = rdA * (hi ? az : ax);
            const float b1B = (hi ? rdB : rvB) * (hi ? by : 1.0f);
            const float b2B = rdB * (hi ? bz : bx);

            accR += raA + raB;
            acc1 += b1A * ax + b1B * bx;
            acc2 += b1A * ay + b1B * by;
            acc3 += b1A * az + b1B * bz;
            acc4 += b2A * ax + b2B * bx;
            acc5 += b2A * ay + b2B * by;
            acc6 += b2A * az + b2B * bz;
        }
        if (idx < s1) {
            const uint2 q = eps[idx];
            const float x = __half2float(__ushort_as_half((unsigned short)(q.x & 0xffff)));
            const float y = __half2float(__ushort_as_half((unsigned short)(q.x >> 16)));
            const float z = __half2float(__ushort_as_half((unsigned short)(q.y & 0xffff)));
            const int   b = (int)(q.y >> 16) * 96 + a;
            const float ra = tabI[b], rv = tabI[b + 32], rd = tabI[b + 64];
            const float b1 = (hi ? rd : rv) * (hi ? y : 1.0f);
            const float b2 = rd * (hi ? z : x);
            accR += ra;
            acc1 += b1 * x; acc2 += b1 * y; acc3 += b1 * z;
            acc4 += b2 * x; acc5 += b2 * y; acc6 += b2 * z;
        }
    } else {
        for (int idx = s0; idx < s1; idx++) {
            const int e = perm[idx];
            const float x0 = ldf(r_ij, 3 * e + 0, f32);
            const float y0 = ldf(r_ij, 3 * e + 1, f32);
            const float z0 = ldf(r_ij, 3 * e + 2, f32);
            const float d2 = x0 * x0 + y0 * y0 + z0 * z0;
            const float inv = rsqrtf(1.0f + 49.0f * d2);
            const float x = 7.0f * x0 * inv, y = 7.0f * y0 * inv, z = 7.0f * z0 * inv;
            const float u = fminf(sqrtf(d2), DMAX) * ((float)(TSIZE - 1) / DMAX);
            const int b = (int)(u + 0.5f) * 96 + a;
            const float ra = tabI[b], rv = tabI[b + 32], rd = tabI[b + 64];
            const float b1 = (hi ? rd : rv) * (hi ? y : 1.0f);
            const float b2 = rd * (hi ? z : x);
            accR += ra;
            acc1 += b1 * x; acc2 += b1 * y; acc3 += b1 * z;
            acc4 += b2 * x; acc5 += b2 * y; acc6 += b2 * z;
        }
    }

    const size_t baseV = (size_t)N * 32;
    const size_t baseD = (size_t)N * 128;
    if (!hi) {
        stf(out, (size_t)n * 32 + a, accR, f32);
        const size_t vb = baseV + (size_t)n * 96 + a * 3;
        stf(out, vb + 0, acc1, f32);
        stf(out, vb + 1, acc2, f32);
        stf(out, vb + 2, acc3, f32);
        const size_t db = baseD + (size_t)n * 288 + a * 9;
        stf(out, db + 0, acc4, f32);
        stf(out, db + 1, acc5, f32);
        stf(out, db + 2, acc6, f32);
    } else {
        const size_t db = baseD + (size_t)n * 288 + a * 9;
        stf(out, db + 3, acc1, f32);
        stf(out, db + 4, acc2, f32);
        stf(out, db + 5, acc3, f32);
        stf(out, db + 6, acc4, f32);
        stf(out, db + 7, acc5, f32);
        stf(out, db + 8, acc6, f32);
    }
}

extern "C" void kernel_launch(void* const* d_in, const int* in_sizes, int n_in,
                              void* d_out, int out_size, void* d_ws, size_t ws_size,
                              hipStream_t stream) {
    const void* r_ij     = d_in[0];
    const void* w_rad    = d_in[1];
    const void* b_rad    = d_in[2];
    const void* w_direct = d_in[3];
    const void* w1       = d_in[4];
    const void* b1       = d_in[5];
    const void* w2       = d_in[6];
    const void* b2       = d_in[7];
    const void* w3       = d_in[8];
    const void* b3       = d_in[9];
    const void* w_v      = d_in[10];
    const void* w_d      = d_in[11];
    const int* edges_src = (const int*)d_in[12];

    const int E = in_sizes[12];
    const int N = out_size / 416;   // 32 + 96 + 288 per node
    const int chunk = (E + HB - 1) / HB;
    const int ntiles = (N + TILE - 1) / TILE;

    // fast path: eps | wcat | flag | tabI | cnt(u16)[ntiles*HB*TILE] | tot | rowstart
    const size_t cntBytes  = (size_t)ntiles * HB * TILE * 2;
    const size_t fastBytes = (size_t)E * 8
                           + ((size_t)W_TOT + 4 + (size_t)TSIZE * 96
                              + (size_t)N + (size_t)(N + 1)) * 4
                           + cntBytes;
    const bool use_fast = ws_size >= fastBytes + 64;

    char* w = (char*)d_ws;
    if (use_fast) {
        uint2* eps    = (uint2*)w;
        float* wcat   = (float*)(w + (size_t)E * 8);
        int* flag     = (int*)(wcat + W_TOT);
        float* tabI   = (float*)(flag + 4);
        unsigned short* cnt = (unsigned short*)(tabI + (size_t)TSIZE * 96);
        int* tot      = (int*)((char*)cnt + ((cntBytes + 3) & ~(size_t)3));
        int* rowstart = tot + N;              // N+1

        k_prep<<<12, 256, 0, stream>>>(
            r_ij, w_rad, b_rad, w_direct, w1, b1, w2, b2, w3, b3, w_v, w_d,
            wcat, flag, nullptr, N);
        k_table<<<TSIZE / EPB, 64 * EPB, 0, stream>>>(wcat, tabI);
        k_hist<<<HB * ntiles, 256, 0, stream>>>(edges_src, E, chunk, cnt, N);
        k_colscan<<<(N + 255) / 256, 256, 0, stream>>>(cnt, tot, N);
        k_scan<<<1, 1024, 0, stream>>>(tot, rowstart, N, E);
        k_place<<<HB * ntiles, 256, 0, stream>>>(edges_src, E, chunk, cnt,
                                                 rowstart, r_ij, flag, eps, N);
        k_nodes<<<(N + NPB - 1) / NPB, 64 * NPB, 0, stream>>>(
            eps, nullptr, r_ij, rowstart, tabI, flag, d_out, N);
    } else {
        // fallback: global-atomic rank path, perm-indexed k_nodes
        int* perm     = (int*)w;              // E
        float* wcat   = (float*)(w + (size_t)E * 4);
        int* flag     = (int*)(wcat + W_TOT);
        float* tabI   = (float*)(flag + 4);
        int* counts   = (int*)(tabI + (size_t)TSIZE * 96);
        int* rowstart = counts + N;           // N+1
        int* rank     = rowstart + N + 1;     // E

        k_prep<<<12 + (N + 255) / 256, 256, 0, stream>>>(
            r_ij, w_rad, b_rad, w_direct, w1, b1, w2, b2, w3, b3, w_v, w_d,
            wcat, flag, counts, N);
        k_table<<<TSIZE / EPB, 64 * EPB, 0, stream>>>(wcat, tabI);
        k_rank_g<<<(E + 255) / 256, 256, 0, stream>>>(edges_src, counts, rank, E);
        k_scan<<<1, 1024, 0, stream>>>(counts, rowstart, N, E);
        k_place_g<<<(E + 255) / 256, 256, 0, stream>>>(edges_src, rank, rowstart,
                                                       perm, E);
        k_nodes<<<(N + NPB - 1) / NPB, 64 * NPB, 0, stream>>>(
            nullptr, perm, r_ij, rowstart, tabI, flag, d_out, N);
    }
}

// Round 9
// 218.782 us; speedup vs baseline: 1.6168x; 1.0623x over previous
//
#include <hip/hip_runtime.h>
#include <hip/hip_bf16.h>
#include <hip/hip_fp16.h>
#include <math.h>

// ---------------------------------------------------------------------------
// DisplacementTensors: rad = MLP(radial_encode(|r|)) depends only on |r| ->
// tabulate [F(d) | F(d)@w_v | F(d)@w_d] (96 f32/row, 8192 nearest-neighbor
// entries, 3 MB, L2-resident).  CSR segment-sum WITHOUT global atomics:
//   k_hist   : 128 chunks x 2 node-tiles; LDS histogram -> u16 cnt
//   k_colscan: 64-thr blocks, per-node prefix over chunks + coarse block sums
//   k_scan2  : wave-scan (shfl) rowstart from tot+coarse (fully parallel)
//   k_place  : LDS cursor, scatter payload in CSR order
//   k_nodes  : one wave per node streams its slice, branch-free accumulate
// Payload: float4 (rs0,rs1,rs2, table BYTE offset) when ws allows (16B),
// else packed uint2 (f16 rs | u16 idx).  dtype (bf16/f32) runtime-detected.
// ---------------------------------------------------------------------------

#define TSIZE 8192
#define DMAX  2.0f           // RBF centers <=1, width 1/8 -> F const beyond ~2
#define NPB   4              // nodes (waves) per block in k_nodes
#define EPB   4              // entries per block in k_table
#define HB    128            // edge chunks
#define TILE  10240          // node-tile size (40 KB LDS)

// f32 concat-weight offsets (floats)
#define O_WRAD 0
#define O_BRAD 256
#define O_WDIR 288
#define O_W1   1312
#define O_B1   3360
#define O_W2   3424
#define O_B2   7520
#define O_W3   7584
#define O_B3   9632
#define O_WV   9664
#define O_WD   10688
#define W_TOT  11712

__device__ __forceinline__ float lrelu(float x) { return x > 0.0f ? x : 0.1f * x; }

__device__ __forceinline__ float ldf(const void* p, int i, bool f32) {
    return f32 ? ((const float*)p)[i]
               : __uint_as_float(((unsigned int)((const unsigned short*)p)[i]) << 16);
}
__device__ __forceinline__ void stf(void* p, size_t i, float v, bool f32) {
    if (f32) ((float*)p)[i] = v;
    else     ((__hip_bfloat16*)p)[i] = __float2bfloat16(v);
}

__device__ __forceinline__ bool detect_f32(const void* r) {
    const unsigned short* p = (const unsigned short*)r;
    int bad = 0;
#pragma unroll 8
    for (int i = 0; i < 128; i++) {
        float v = __uint_as_float(((unsigned int)p[i]) << 16);
        bad |= (!isfinite(v) || fabsf(v) > 1e5f) ? 1 : 0;
    }
    return bad != 0;
}

// --- prep: flag store | weight->f32 concat | (fallback) zero counts --------
__global__ void k_prep(const void* __restrict__ r_ij,
                       const void* w_rad, const void* b_rad, const void* w_direct,
                       const void* w1, const void* b1, const void* w2, const void* b2,
                       const void* w3, const void* b3, const void* w_v, const void* w_d,
                       float* __restrict__ wcat, int* __restrict__ flag,
                       int* __restrict__ counts, int N) {
    const int b = blockIdx.x;
    if (b == 0) {
        if (threadIdx.x == 0) flag[0] = detect_f32(r_ij) ? 1 : 0;
    } else if (b <= 11) {
        const bool f32 = detect_f32(r_ij);
        const void* src; int cnt; int off;
        switch (b) {
            case 1:  src = w_rad;    cnt = 256;  off = O_WRAD; break;
            case 2:  src = b_rad;    cnt = 32;   off = O_BRAD; break;
            case 3:  src = w_direct; cnt = 1024; off = O_WDIR; break;
            case 4:  src = w1;       cnt = 2048; off = O_W1;   break;
            case 5:  src = b1;       cnt = 64;   off = O_B1;   break;
            case 6:  src = w2;       cnt = 4096; off = O_W2;   break;
            case 7:  src = b2;       cnt = 64;   off = O_B2;   break;
            case 8:  src = w3;       cnt = 2048; off = O_W3;   break;
            case 9:  src = b3;       cnt = 32;   off = O_B3;   break;
            case 10: src = w_v;      cnt = 1024; off = O_WV;   break;
            default: src = w_d;      cnt = 1024; off = O_WD;   break;
        }
        for (int i = threadIdx.x; i < cnt; i += blockDim.x)
            wcat[off + i] = ldf(src, i, f32);
    } else if (counts) {
        int i = (b - 12) * blockDim.x + threadIdx.x;
        if (i < N) counts[i] = 0;
    }
}

// --- LUT build: 4 entries/block, wave = entry, lane = neuron ---------------
__global__ void __launch_bounds__(64 * EPB) k_table(const float* __restrict__ wcat,
                                                    float* __restrict__ tabI) {
    __shared__ float Lh[EPB][32], Lt1[EPB][64], Lt2[EPB][64], Lrad[EPB][32];

    const int s = threadIdx.x >> 6;
    const int j = threadIdx.x & 63;
    const int e = blockIdx.x * EPB + s;
    const float d = (float)e * (DMAX / (float)(TSIZE - 1));

    float enc[8];
#pragma unroll
    for (int k = 0; k < 8; k++) {
        float t = (d - (float)k * (1.0f / 7.0f)) * 8.0f;
        enc[k] = expf(-t * t);
    }

    if (j < 32) {
        float hv = wcat[O_BRAD + j];
#pragma unroll
        for (int k = 0; k < 8; k++) hv = fmaf(enc[k], wcat[O_WRAD + k * 32 + j], hv);
        Lh[s][j] = hv;
    }
    __syncthreads();

    {
        float v = wcat[O_B1 + j];
#pragma unroll
        for (int i = 0; i < 32; i++) v = fmaf(Lh[s][i], wcat[O_W1 + i * 64 + j], v);
        Lt1[s][j] = lrelu(v);
    }
    __syncthreads();

    {
        float v = wcat[O_B2 + j];
#pragma unroll
        for (int i = 0; i < 64; i++) v = fmaf(Lt1[s][i], wcat[O_W2 + i * 64 + j], v);
        Lt2[s][j] = lrelu(v);
    }
    __syncthreads();

    if (j < 32) {
        float v = wcat[O_B3 + j];
#pragma unroll
        for (int i = 0; i < 64; i++) v = fmaf(Lt2[s][i], wcat[O_W3 + i * 32 + j], v);
#pragma unroll
        for (int i = 0; i < 32; i++) v = fmaf(Lh[s][i], wcat[O_WDIR + i * 32 + j], v);
        Lrad[s][j] = v;
        tabI[e * 96 + j] = v;
    }
    __syncthreads();

    if (j < 32) {
        float sv = 0.0f, sd = 0.0f;
#pragma unroll
        for (int i = 0; i < 32; i++) {
            float ri = Lrad[s][i];
            sv = fmaf(ri, wcat[O_WV + i * 32 + j], sv);
            sd = fmaf(ri, wcat[O_WD + i * 32 + j], sd);
        }
        tabI[e * 96 + 32 + j] = sv;
        tabI[e * 96 + 64 + j] = sd;
    }
}

// --- CSR pass 1: per-(chunk,tile) LDS histogram -> u16 cnt -----------------
__global__ void __launch_bounds__(256) k_hist(const int* __restrict__ src, int E,
                                              int chunk,
                                              unsigned short* __restrict__ cnt,
                                              int N) {
    __shared__ int lcnt[TILE];
    const int b = blockIdx.x % HB;
    const int t = blockIdx.x / HB;
    const int lo = b * chunk;
    const int hi = min(lo + chunk, E);
    const int t0 = t * TILE;
    const int tl = min(TILE, N - t0);

    for (int i = threadIdx.x; i < tl; i += 256) lcnt[i] = 0;
    __syncthreads();
    for (int e = lo + threadIdx.x; e < hi; e += 256) {
        const int s = src[e] - t0;
        if ((unsigned)s < (unsigned)tl) atomicAdd(&lcnt[s], 1);
    }
    __syncthreads();
    unsigned short* out = cnt + (size_t)(t * HB + b) * TILE;
    for (int i = threadIdx.x; i < tl; i += 256)
        out[i] = (unsigned short)lcnt[i];
}

// --- CSR pass 2: per-node prefix over chunks; coarse sum per 64-node block -
__global__ void __launch_bounds__(64) k_colscan(unsigned short* __restrict__ cnt,
                                                int* __restrict__ tot,
                                                int* __restrict__ coarse, int N) {
    const int lane = threadIdx.x;
    const int n = blockIdx.x * 64 + lane;
    int run = 0;
    if (n < N) {
        const int t = n / TILE;
        const int nl = n % TILE;
        unsigned short* col = cnt + (size_t)(t * HB) * TILE + nl;
#pragma unroll 4
        for (int b = 0; b < HB; b++) {
            int c = col[(size_t)b * TILE];
            col[(size_t)b * TILE] = (unsigned short)run;
            run += c;
        }
        tot[n] = run;
    }
    int s = run;
    for (int off = 32; off > 0; off >>= 1) s += __shfl_down(s, off);
    if (lane == 0) coarse[blockIdx.x] = s;
}

// --- CSR pass 3: rowstart via coarse prefix + wave scan (fully parallel) ---
__global__ void __launch_bounds__(64) k_scan2(const int* __restrict__ tot,
                                              const int* __restrict__ coarse,
                                              int* __restrict__ rowstart, int N) {
    const int lane = threadIdx.x;
    const int b = blockIdx.x;
    int cpre = 0;
    if (lane == 0) for (int i = 0; i < b; i++) cpre += coarse[i];
    cpre = __shfl(cpre, 0);
    const int n = b * 64 + lane;
    const int v = (n < N) ? tot[n] : 0;
    int inc = v;
    for (int off = 1; off < 64; off <<= 1) {
        int y = __shfl_up(inc, off);
        if (lane >= off) inc += y;
    }
    if (n < N) rowstart[n] = cpre + inc - v;
    if (n == N - 1) rowstart[N] = cpre + inc;
}

// --- CSR pass 4: place payload via LDS cursor ------------------------------
template <bool P16>
__global__ void __launch_bounds__(256) k_place(
        const int* __restrict__ src, int E, int chunk,
        const unsigned short* __restrict__ cnt, const int* __restrict__ rowstart,
        const void* __restrict__ r_ij, const int* __restrict__ flag,
        void* __restrict__ epsv, int N) {
    __shared__ int cur[TILE];
    const int b = blockIdx.x % HB;
    const int t = blockIdx.x / HB;
    const int lo = b * chunk;
    const int hi = min(lo + chunk, E);
    const int t0 = t * TILE;
    const int tl = min(TILE, N - t0);
    const bool f32 = flag[0] != 0;

    const unsigned short* base = cnt + (size_t)(t * HB + b) * TILE;
    for (int i = threadIdx.x; i < tl; i += 256)
        cur[i] = rowstart[t0 + i] + (int)base[i];
    __syncthreads();
    for (int e = lo + threadIdx.x; e < hi; e += 256) {
        const int s = src[e] - t0;
        if ((unsigned)s < (unsigned)tl) {
            const int pos = atomicAdd(&cur[s], 1);
            const float x = ldf(r_ij, 3 * e + 0, f32);
            const float y = ldf(r_ij, 3 * e + 1, f32);
            const float z = ldf(r_ij, 3 * e + 2, f32);
            const float d2 = x * x + y * y + z * z;
            const float inv = rsqrtf(1.0f + 49.0f * d2);  // tens_sigmoid(7r)
            const float u = fminf(sqrtf(d2), DMAX) * ((float)(TSIZE - 1) / DMAX);
            const int ti = (int)(u + 0.5f);               // nearest, <= TSIZE-1
            const float rs0 = 7.0f * x * inv, rs1 = 7.0f * y * inv,
                        rs2 = 7.0f * z * inv;
            if (P16) {
                ((float4*)epsv)[pos] =
                    make_float4(rs0, rs1, rs2, __int_as_float(ti * 384));
            } else {
                const unsigned int h0 = __half_as_ushort(__float2half(rs0));
                const unsigned int h1 = __half_as_ushort(__float2half(rs1));
                const unsigned int h2 = __half_as_ushort(__float2half(rs2));
                ((uint2*)epsv)[pos] =
                    make_uint2(h0 | (h1 << 16), h2 | ((unsigned)ti << 16));
            }
        }
    }
}

// --- per-node accumulation: one wave per node, branch-free -----------------
template <bool P16>
__global__ void __launch_bounds__(64 * NPB) k_nodes(
    const void* __restrict__ epsv,
    const int* __restrict__ rowstart,
    const float* __restrict__ tabI,
    const int* __restrict__ flag,
    void* __restrict__ out, int N) {
    const int wave = threadIdx.x >> 6;
    const int lane = threadIdx.x & 63;
    const int n = blockIdx.x * NPB + wave;
    if (n >= N) return;
    const int a = lane & 31;
    const bool hi = (lane >> 5) != 0;
    const bool f32 = flag[0] != 0;
    const char* tabA = (const char*)tabI + (a << 2);

    const int s0 = rowstart[n];
    const int s1 = rowstart[n + 1];

    float accR = 0.f, acc1 = 0.f, acc2 = 0.f, acc3 = 0.f,
          acc4 = 0.f, acc5 = 0.f, acc6 = 0.f;

    int idx = s0;
    for (; idx + 1 < s1; idx += 2) {          // unroll x2: overlap loads
        float ax, ay, az, bx, by, bz;
        const float *pA, *pB;
        if (P16) {
            const float4 qa = ((const float4*)epsv)[idx];
            const float4 qb = ((const float4*)epsv)[idx + 1];
            ax = qa.x; ay = qa.y; az = qa.z;
            bx = qb.x; by = qb.y; bz = qb.z;
            pA = (const float*)(tabA + __float_as_int(qa.w));
            pB = (const float*)(tabA + __float_as_int(qb.w));
        } else {
            const uint2 qa = ((const uint2*)epsv)[idx];
            const uint2 qb = ((const uint2*)epsv)[idx + 1];
            ax = __half2float(__ushort_as_half((unsigned short)(qa.x & 0xffff)));
            ay = __half2float(__ushort_as_half((unsigned short)(qa.x >> 16)));
            az = __half2float(__ushort_as_half((unsigned short)(qa.y & 0xffff)));
            bx = __half2float(__ushort_as_half((unsigned short)(qb.x & 0xffff)));
            by = __half2float(__ushort_as_half((unsigned short)(qb.x >> 16)));
            bz = __half2float(__ushort_as_half((unsigned short)(qb.y & 0xffff)));
            pA = (const float*)(tabA + (int)(qa.y >> 16) * 384);
            pB = (const float*)(tabA + (int)(qb.y >> 16) * 384);
        }
        const float raA = pA[0], rvA = pA[32], rdA = pA[64];
        const float raB = pB[0], rvB = pB[32], rdB = pB[64];

        const float b1A = (hi ? rdA : rvA) * (hi ? ay : 1.0f);
        const float b2A = rdA * (hi ? az : ax);
        const float b1B = (hi ? rdB : rvB) * (hi ? by : 1.0f);
        const float b2B = rdB * (hi ? bz : bx);

        accR += raA + raB;
        acc1 += b1A * ax + b1B * bx;
        acc2 += b1A * ay + b1B * by;
        acc3 += b1A * az + b1B * bz;
        acc4 += b2A * ax + b2B * bx;
        acc5 += b2A * ay + b2B * by;
        acc6 += b2A * az + b2B * bz;
    }
    if (idx < s1) {                            // tail
        float x, y, z;
        const float* p;
        if (P16) {
            const float4 q = ((const float4*)epsv)[idx];
            x = q.x; y = q.y; z = q.z;
            p = (const float*)(tabA + __float_as_int(q.w));
        } else {
            const uint2 q = ((const uint2*)epsv)[idx];
            x = __half2float(__ushort_as_half((unsigned short)(q.x & 0xffff)));
            y = __half2float(__ushort_as_half((unsigned short)(q.x >> 16)));
            z = __half2float(__ushort_as_half((unsigned short)(q.y & 0xffff)));
            p = (const float*)(tabA + (int)(q.y >> 16) * 384);
        }
        const float ra = p[0], rv = p[32], rd = p[64];
        const float b1 = (hi ? rd : rv) * (hi ? y : 1.0f);
        const float b2 = rd * (hi ? z : x);
        accR += ra;
        acc1 += b1 * x; acc2 += b1 * y; acc3 += b1 * z;
        acc4 += b2 * x; acc5 += b2 * y; acc6 += b2 * z;
    }

    const size_t baseV = (size_t)N * 32;
    const size_t baseD = (size_t)N * 128;
    if (!hi) {
        stf(out, (size_t)n * 32 + a, accR, f32);
        const size_t vb = baseV + (size_t)n * 96 + a * 3;
        stf(out, vb + 0, acc1, f32);
        stf(out, vb + 1, acc2, f32);
        stf(out, vb + 2, acc3, f32);
        const size_t db = baseD + (size_t)n * 288 + a * 9;
        stf(out, db + 0, acc4, f32);
        stf(out, db + 1, acc5, f32);
        stf(out, db + 2, acc6, f32);
    } else {
        const size_t db = baseD + (size_t)n * 288 + a * 9;
        stf(out, db + 3, acc1, f32);
        stf(out, db + 4, acc2, f32);
        stf(out, db + 5, acc3, f32);
        stf(out, db + 6, acc4, f32);
        stf(out, db + 7, acc5, f32);
        stf(out, db + 8, acc6, f32);
    }
}

// --- fallback CSR (global atomics) + perm-based nodes ----------------------
__global__ void k_rank_g(const int* __restrict__ src, int* __restrict__ counts,
                         int* __restrict__ rank, int E) {
    int e = blockIdx.x * blockDim.x + threadIdx.x;
    if (e < E) rank[e] = atomicAdd(&counts[src[e]], 1);
}
__global__ void k_scan_g(const int* __restrict__ counts, int* __restrict__ rowstart,
                         int N, int E) {
    __shared__ int part[1024];
    const int t = threadIdx.x;
    const int CH = (N + 1023) / 1024;
    const int lo = t * CH;
    const int hi = min(lo + CH, N);
    int s = 0;
    for (int i = lo; i < hi; i++) s += counts[i];
    part[t] = s;
    __syncthreads();
    for (int off = 1; off < 1024; off <<= 1) {
        int v = part[t];
        int w = (t >= off) ? part[t - off] : 0;
        __syncthreads();
        part[t] = v + w;
        __syncthreads();
    }
    int run = (t == 0) ? 0 : part[t - 1];
    for (int i = lo; i < hi; i++) { rowstart[i] = run; run += counts[i]; }
    if (t == 0) rowstart[N] = E;
}
__global__ void k_place_g(const int* __restrict__ src, const int* __restrict__ rank,
                          const int* __restrict__ rowstart,
                          int* __restrict__ perm, int E) {
    int e = blockIdx.x * blockDim.x + threadIdx.x;
    if (e < E) perm[rowstart[src[e]] + rank[e]] = e;
}
__global__ void __launch_bounds__(64 * NPB) k_nodes_fb(
    const int* __restrict__ perm, const void* __restrict__ r_ij,
    const int* __restrict__ rowstart, const float* __restrict__ tabI,
    const int* __restrict__ flag, void* __restrict__ out, int N) {
    const int wave = threadIdx.x >> 6;
    const int lane = threadIdx.x & 63;
    const int n = blockIdx.x * NPB + wave;
    if (n >= N) return;
    const int a = lane & 31;
    const bool hi = (lane >> 5) != 0;
    const bool f32 = flag[0] != 0;
    const int s0 = rowstart[n], s1 = rowstart[n + 1];
    float accR = 0.f, acc1 = 0.f, acc2 = 0.f, acc3 = 0.f,
          acc4 = 0.f, acc5 = 0.f, acc6 = 0.f;
    for (int idx = s0; idx < s1; idx++) {
        const int e = perm[idx];
        const float x0 = ldf(r_ij, 3 * e + 0, f32);
        const float y0 = ldf(r_ij, 3 * e + 1, f32);
        const float z0 = ldf(r_ij, 3 * e + 2, f32);
        const float d2 = x0 * x0 + y0 * y0 + z0 * z0;
        const float inv = rsqrtf(1.0f + 49.0f * d2);
        const float x = 7.0f * x0 * inv, y = 7.0f * y0 * inv, z = 7.0f * z0 * inv;
        const float u = fminf(sqrtf(d2), DMAX) * ((float)(TSIZE - 1) / DMAX);
        const int b = (int)(u + 0.5f) * 96 + a;
        const float ra = tabI[b], rv = tabI[b + 32], rd = tabI[b + 64];
        const float b1 = (hi ? rd : rv) * (hi ? y : 1.0f);
        const float b2 = rd * (hi ? z : x);
        accR += ra;
        acc1 += b1 * x; acc2 += b1 * y; acc3 += b1 * z;
        acc4 += b2 * x; acc5 += b2 * y; acc6 += b2 * z;
    }
    const size_t baseV = (size_t)N * 32;
    const size_t baseD = (size_t)N * 128;
    if (!hi) {
        stf(out, (size_t)n * 32 + a, accR, f32);
        const size_t vb = baseV + (size_t)n * 96 + a * 3;
        stf(out, vb + 0, acc1, f32);
        stf(out, vb + 1, acc2, f32);
        stf(out, vb + 2, acc3, f32);
        const size_t db = baseD + (size_t)n * 288 + a * 9;
        stf(out, db + 0, acc4, f32);
        stf(out, db + 1, acc5, f32);
        stf(out, db + 2, acc6, f32);
    } else {
        const size_t db = baseD + (size_t)n * 288 + a * 9;
        stf(out, db + 3, acc1, f32);
        stf(out, db + 4, acc2, f32);
        stf(out, db + 5, acc3, f32);
        stf(out, db + 6, acc4, f32);
        stf(out, db + 7, acc5, f32);
        stf(out, db + 8, acc6, f32);
    }
}

extern "C" void kernel_launch(void* const* d_in, const int* in_sizes, int n_in,
                              void* d_out, int out_size, void* d_ws, size_t ws_size,
                              hipStream_t stream) {
    const void* r_ij     = d_in[0];
    const void* w_rad    = d_in[1];
    const void* b_rad    = d_in[2];
    const void* w_direct = d_in[3];
    const void* w1       = d_in[4];
    const void* b1       = d_in[5];
    const void* w2       = d_in[6];
    const void* b2       = d_in[7];
    const void* w3       = d_in[8];
    const void* b3       = d_in[9];
    const void* w_v      = d_in[10];
    const void* w_d      = d_in[11];
    const int* edges_src = (const int*)d_in[12];

    const int E = in_sizes[12];
    const int N = out_size / 416;   // 32 + 96 + 288 per node
    const int chunk = (E + HB - 1) / HB;
    const int ntiles = (N + TILE - 1) / TILE;
    const int NB = (N + 63) / 64;

    const size_t cntBytes  = (size_t)ntiles * HB * TILE * 2;
    const size_t tailBytes = ((size_t)W_TOT + 4) * 4 + (size_t)TSIZE * 96 * 4
                           + cntBytes + ((size_t)N + NB + N + 1) * 4;
    const bool p16 = ws_size >= (size_t)E * 16 + tailBytes + 64;
    const bool p8  = !p16 && ws_size >= (size_t)E * 8 + tailBytes + 64;

    char* w = (char*)d_ws;
    if (p16 || p8) {
        const size_t slot = (size_t)E * (p16 ? 16 : 8);
        void* eps     = (void*)w;
        float* wcat   = (float*)(w + slot);
        int* flag     = (int*)(wcat + W_TOT);
        float* tabI   = (float*)(flag + 4);
        unsigned short* cnt = (unsigned short*)(tabI + (size_t)TSIZE * 96);
        int* tot      = (int*)((char*)cnt + cntBytes);
        int* coarse   = tot + N;              // NB entries
        int* rowstart = coarse + NB;          // N+1

        k_prep<<<12, 256, 0, stream>>>(
            r_ij, w_rad, b_rad, w_direct, w1, b1, w2, b2, w3, b3, w_v, w_d,
            wcat, flag, nullptr, N);
        k_table<<<TSIZE / EPB, 64 * EPB, 0, stream>>>(wcat, tabI);
        k_hist<<<HB * ntiles, 256, 0, stream>>>(edges_src, E, chunk, cnt, N);
        k_colscan<<<NB, 64, 0, stream>>>(cnt, tot, coarse, N);
        k_scan2<<<NB, 64, 0, stream>>>(tot, coarse, rowstart, N);
        if (p16) {
            k_place<true><<<HB * ntiles, 256, 0, stream>>>(
                edges_src, E, chunk, cnt, rowstart, r_ij, flag, eps, N);
            k_nodes<true><<<(N + NPB - 1) / NPB, 64 * NPB, 0, stream>>>(
                eps, rowstart, tabI, flag, d_out, N);
        } else {
            k_place<false><<<HB * ntiles, 256, 0, stream>>>(
                edges_src, E, chunk, cnt, rowstart, r_ij, flag, eps, N);
            k_nodes<false><<<(N + NPB - 1) / NPB, 64 * NPB, 0, stream>>>(
                eps, rowstart, tabI, flag, d_out, N);
        }
    } else {
        // fallback: global-atomic rank path, perm-indexed nodes
        int* perm     = (int*)w;              // E
        float* wcat   = (float*)(w + (size_t)E * 4);
        int* flag     = (int*)(wcat + W_TOT);
        float* tabI   = (float*)(flag + 4);
        int* counts   = (int*)(tabI + (size_t)TSIZE * 96);
        int* rowstart = counts + N;           // N+1
        int* rank     = rowstart + N + 1;     // E

        k_prep<<<12 + (N + 255) / 256, 256, 0, stream>>>(
            r_ij, w_rad, b_rad, w_direct, w1, b1, w2, b2, w3, b3, w_v, w_d,
            wcat, flag, counts, N);
        k_table<<<TSIZE / EPB, 64 * EPB, 0, stream>>>(wcat, tabI);
        k_rank_g<<<(E + 255) / 256, 256, 0, stream>>>(edges_src, counts, rank, E);
        k_scan_g<<<1, 1024, 0, stream>>>(counts, rowstart, N, E);
        k_place_g<<<(E + 255) / 256, 256, 0, stream>>>(edges_src, rank, rowstart,
                                                       perm, E);
        k_nodes_fb<<<(N + NPB - 1) / NPB, 64 * NPB, 0, stream>>>(
            perm, r_ij, rowstart, tabI, flag, d_out, N);
    }
}

// Round 10
// 207.684 us; speedup vs baseline: 1.7032x; 1.0534x over previous
//
#include <hip/hip_runtime.h>
#include <hip/hip_bf16.h>
#include <hip/hip_fp16.h>
#include <math.h>

// ---------------------------------------------------------------------------
// DisplacementTensors: rad = MLP(radial_encode(|r|)) depends only on |r| ->
// tabulate [F(d) | F(d)@w_v | F(d)@w_d] (96 f32/row, 8192 nearest-neighbor
// entries, 3 MB, L2-resident).  CSR segment-sum WITHOUT global atomics:
//   k_hist   : 128 chunks x 2 node-tiles; LDS histogram -> u16 cnt
//   k_colscan: per-node prefix over chunks + coarse block sums
//   k_scan2  : rowstart; coarse prefix summed COOPERATIVELY (R9 had a
//              312-load serial chain on lane 0 -> ~20 us; fixed)
//   k_place  : LDS cursor, scatter payload in CSR order
//   k_nodes2 : TWO nodes per wave (lane = half x channel), each lane owns all
//              13 outputs of its channel; main loop to min(lenA,lenB) with no
//              predication, divergent tail to max.  Halves VMEM/edge and
//              removes all cndmask selects vs the 1-node/wave version.
// Payload: float4 (rs0,rs1,rs2, table BYTE offset) when ws allows, else
// packed uint2 (f16 rs | u16 idx).  dtype (bf16/f32) runtime-detected.
// ---------------------------------------------------------------------------

#define TSIZE 8192
#define DMAX  2.0f           // RBF centers <=1, width 1/8 -> F const beyond ~2
#define EPB   4              // entries per block in k_table
#define HB    128            // edge chunks
#define TILE  10240          // node-tile size (40 KB LDS)
#define NPB   4              // waves per block in k_nodes2 (8 nodes/block)

// f32 concat-weight offsets (floats)
#define O_WRAD 0
#define O_BRAD 256
#define O_WDIR 288
#define O_W1   1312
#define O_B1   3360
#define O_W2   3424
#define O_B2   7520
#define O_W3   7584
#define O_B3   9632
#define O_WV   9664
#define O_WD   10688
#define W_TOT  11712

__device__ __forceinline__ float lrelu(float x) { return x > 0.0f ? x : 0.1f * x; }

__device__ __forceinline__ float ldf(const void* p, int i, bool f32) {
    return f32 ? ((const float*)p)[i]
               : __uint_as_float(((unsigned int)((const unsigned short*)p)[i]) << 16);
}
__device__ __forceinline__ void stf(void* p, size_t i, float v, bool f32) {
    if (f32) ((float*)p)[i] = v;
    else     ((__hip_bfloat16*)p)[i] = __float2bfloat16(v);
}

__device__ __forceinline__ bool detect_f32(const void* r) {
    const unsigned short* p = (const unsigned short*)r;
    int bad = 0;
#pragma unroll 8
    for (int i = 0; i < 128; i++) {
        float v = __uint_as_float(((unsigned int)p[i]) << 16);
        bad |= (!isfinite(v) || fabsf(v) > 1e5f) ? 1 : 0;
    }
    return bad != 0;
}

// --- prep: flag store | weight->f32 concat | (fallback) zero counts --------
__global__ void k_prep(const void* __restrict__ r_ij,
                       const void* w_rad, const void* b_rad, const void* w_direct,
                       const void* w1, const void* b1, const void* w2, const void* b2,
                       const void* w3, const void* b3, const void* w_v, const void* w_d,
                       float* __restrict__ wcat, int* __restrict__ flag,
                       int* __restrict__ counts, int N) {
    const int b = blockIdx.x;
    if (b == 0) {
        if (threadIdx.x == 0) flag[0] = detect_f32(r_ij) ? 1 : 0;
    } else if (b <= 11) {
        const bool f32 = detect_f32(r_ij);
        const void* src; int cnt; int off;
        switch (b) {
            case 1:  src = w_rad;    cnt = 256;  off = O_WRAD; break;
            case 2:  src = b_rad;    cnt = 32;   off = O_BRAD; break;
            case 3:  src = w_direct; cnt = 1024; off = O_WDIR; break;
            case 4:  src = w1;       cnt = 2048; off = O_W1;   break;
            case 5:  src = b1;       cnt = 64;   off = O_B1;   break;
            case 6:  src = w2;       cnt = 4096; off = O_W2;   break;
            case 7:  src = b2;       cnt = 64;   off = O_B2;   break;
            case 8:  src = w3;       cnt = 2048; off = O_W3;   break;
            case 9:  src = b3;       cnt = 32;   off = O_B3;   break;
            case 10: src = w_v;      cnt = 1024; off = O_WV;   break;
            default: src = w_d;      cnt = 1024; off = O_WD;   break;
        }
        for (int i = threadIdx.x; i < cnt; i += blockDim.x)
            wcat[off + i] = ldf(src, i, f32);
    } else if (counts) {
        int i = (b - 12) * blockDim.x + threadIdx.x;
        if (i < N) counts[i] = 0;
    }
}

// --- LUT build: 4 entries/block, wave = entry, lane = neuron ---------------
__global__ void __launch_bounds__(64 * EPB) k_table(const float* __restrict__ wcat,
                                                    float* __restrict__ tabI) {
    __shared__ float Lh[EPB][32], Lt1[EPB][64], Lt2[EPB][64], Lrad[EPB][32];

    const int s = threadIdx.x >> 6;
    const int j = threadIdx.x & 63;
    const int e = blockIdx.x * EPB + s;
    const float d = (float)e * (DMAX / (float)(TSIZE - 1));

    float enc[8];
#pragma unroll
    for (int k = 0; k < 8; k++) {
        float t = (d - (float)k * (1.0f / 7.0f)) * 8.0f;
        enc[k] = expf(-t * t);
    }

    if (j < 32) {
        float hv = wcat[O_BRAD + j];
#pragma unroll
        for (int k = 0; k < 8; k++) hv = fmaf(enc[k], wcat[O_WRAD + k * 32 + j], hv);
        Lh[s][j] = hv;
    }
    __syncthreads();

    {
        float v = wcat[O_B1 + j];
#pragma unroll
        for (int i = 0; i < 32; i++) v = fmaf(Lh[s][i], wcat[O_W1 + i * 64 + j], v);
        Lt1[s][j] = lrelu(v);
    }
    __syncthreads();

    {
        float v = wcat[O_B2 + j];
#pragma unroll
        for (int i = 0; i < 64; i++) v = fmaf(Lt1[s][i], wcat[O_W2 + i * 64 + j], v);
        Lt2[s][j] = lrelu(v);
    }
    __syncthreads();

    if (j < 32) {
        float v = wcat[O_B3 + j];
#pragma unroll
        for (int i = 0; i < 64; i++) v = fmaf(Lt2[s][i], wcat[O_W3 + i * 32 + j], v);
#pragma unroll
        for (int i = 0; i < 32; i++) v = fmaf(Lh[s][i], wcat[O_WDIR + i * 32 + j], v);
        Lrad[s][j] = v;
        tabI[e * 96 + j] = v;
    }
    __syncthreads();

    if (j < 32) {
        float sv = 0.0f, sd = 0.0f;
#pragma unroll
        for (int i = 0; i < 32; i++) {
            float ri = Lrad[s][i];
            sv = fmaf(ri, wcat[O_WV + i * 32 + j], sv);
            sd = fmaf(ri, wcat[O_WD + i * 32 + j], sd);
        }
        tabI[e * 96 + 32 + j] = sv;
        tabI[e * 96 + 64 + j] = sd;
    }
}

// --- CSR pass 1: per-(chunk,tile) LDS histogram -> u16 cnt -----------------
__global__ void __launch_bounds__(256) k_hist(const int* __restrict__ src, int E,
                                              int chunk,
                                              unsigned short* __restrict__ cnt,
                                              int N) {
    __shared__ int lcnt[TILE];
    const int b = blockIdx.x % HB;
    const int t = blockIdx.x / HB;
    const int lo = b * chunk;
    const int hi = min(lo + chunk, E);
    const int t0 = t * TILE;
    const int tl = min(TILE, N - t0);

    for (int i = threadIdx.x; i < tl; i += 256) lcnt[i] = 0;
    __syncthreads();
    for (int e = lo + threadIdx.x; e < hi; e += 256) {
        const int s = src[e] - t0;
        if ((unsigned)s < (unsigned)tl) atomicAdd(&lcnt[s], 1);
    }
    __syncthreads();
    unsigned short* out = cnt + (size_t)(t * HB + b) * TILE;
    for (int i = threadIdx.x; i < tl; i += 256)
        out[i] = (unsigned short)lcnt[i];
}

// --- CSR pass 2: per-node prefix over chunks; coarse sum per 64-node block -
__global__ void __launch_bounds__(64) k_colscan(unsigned short* __restrict__ cnt,
                                                int* __restrict__ tot,
                                                int* __restrict__ coarse, int N) {
    const int lane = threadIdx.x;
    const int n = blockIdx.x * 64 + lane;
    int run = 0;
    if (n < N) {
        const int t = n / TILE;
        const int nl = n % TILE;
        unsigned short* col = cnt + (size_t)(t * HB) * TILE + nl;
#pragma unroll 4
        for (int b = 0; b < HB; b++) {
            int c = col[(size_t)b * TILE];
            col[(size_t)b * TILE] = (unsigned short)run;
            run += c;
        }
        tot[n] = run;
    }
    int s = run;
    for (int off = 32; off > 0; off >>= 1) s += __shfl_down(s, off);
    if (lane == 0) coarse[blockIdx.x] = s;
}

// --- CSR pass 3: rowstart; coarse prefix summed cooperatively --------------
__global__ void __launch_bounds__(64) k_scan2(const int* __restrict__ tot,
                                              const int* __restrict__ coarse,
                                              int* __restrict__ rowstart, int N) {
    const int lane = threadIdx.x;
    const int b = blockIdx.x;
    // cooperative sum of coarse[0..b) (R9: serial on lane 0 -> ~20 us)
    int cp = 0;
    for (int j = lane; j < b; j += 64) cp += coarse[j];
    for (int off = 32; off > 0; off >>= 1) cp += __shfl_down(cp, off);
    const int cpre = __shfl(cp, 0);

    const int n = b * 64 + lane;
    const int v = (n < N) ? tot[n] : 0;
    int inc = v;
    for (int off = 1; off < 64; off <<= 1) {
        int y = __shfl_up(inc, off);
        if (lane >= off) inc += y;
    }
    if (n < N) rowstart[n] = cpre + inc - v;
    if (n == N - 1) rowstart[N] = cpre + inc;
}

// --- CSR pass 4: place payload via LDS cursor ------------------------------
template <bool P16>
__global__ void __launch_bounds__(256) k_place(
        const int* __restrict__ src, int E, int chunk,
        const unsigned short* __restrict__ cnt, const int* __restrict__ rowstart,
        const void* __restrict__ r_ij, const int* __restrict__ flag,
        void* __restrict__ epsv, int N) {
    __shared__ int cur[TILE];
    const int b = blockIdx.x % HB;
    const int t = blockIdx.x / HB;
    const int lo = b * chunk;
    const int hi = min(lo + chunk, E);
    const int t0 = t * TILE;
    const int tl = min(TILE, N - t0);
    const bool f32 = flag[0] != 0;

    const unsigned short* base = cnt + (size_t)(t * HB + b) * TILE;
    for (int i = threadIdx.x; i < tl; i += 256)
        cur[i] = rowstart[t0 + i] + (int)base[i];
    __syncthreads();
    for (int e = lo + threadIdx.x; e < hi; e += 256) {
        const int s = src[e] - t0;
        if ((unsigned)s < (unsigned)tl) {
            const int pos = atomicAdd(&cur[s], 1);
            const float x = ldf(r_ij, 3 * e + 0, f32);
            const float y = ldf(r_ij, 3 * e + 1, f32);
            const float z = ldf(r_ij, 3 * e + 2, f32);
            const float d2 = x * x + y * y + z * z;
            const float inv = rsqrtf(1.0f + 49.0f * d2);  // tens_sigmoid(7r)
            const float u = fminf(sqrtf(d2), DMAX) * ((float)(TSIZE - 1) / DMAX);
            const int ti = (int)(u + 0.5f);               // nearest, <= TSIZE-1
            const float rs0 = 7.0f * x * inv, rs1 = 7.0f * y * inv,
                        rs2 = 7.0f * z * inv;
            if (P16) {
                ((float4*)epsv)[pos] =
                    make_float4(rs0, rs1, rs2, __int_as_float(ti * 384));
            } else {
                const unsigned int h0 = __half_as_ushort(__float2half(rs0));
                const unsigned int h1 = __half_as_ushort(__float2half(rs1));
                const unsigned int h2 = __half_as_ushort(__float2half(rs2));
                ((uint2*)epsv)[pos] =
                    make_uint2(h0 | (h1 << 16), h2 | ((unsigned)ti << 16));
            }
        }
    }
}

// --- per-node accumulation: TWO nodes per wave -----------------------------
// lane = (half = lane>>5, channel a = lane&31); each lane owns all 13 outputs
// of channel a of node n0+half.  Main loop to min(lenA,lenB): no predication.
template <bool P16>
__global__ void __launch_bounds__(64 * NPB) k_nodes2(
    const void* __restrict__ epsv,
    const int* __restrict__ rowstart,
    const float* __restrict__ tabI,
    const int* __restrict__ flag,
    void* __restrict__ out, int N) {
    const int wave = threadIdx.x >> 6;
    const int lane = threadIdx.x & 63;
    const int n0 = (blockIdx.x * NPB + wave) * 2;
    const int a = lane & 31;
    const int half = lane >> 5;
    const int myn = n0 + half;
    const bool f32 = flag[0] != 0;
    const char* tabA = (const char*)tabI + (a << 2);

    int s0 = 0, s1 = 0;
    if (myn < N) { s0 = rowstart[myn]; s1 = rowstart[myn + 1]; }
    const int mylen = s1 - s0;
    const int lenA = __shfl(mylen, 0);
    const int lenB = __shfl(mylen, 32);
    const int minl = min(lenA, lenB);
    const int maxl = max(lenA, lenB);

    float accA = 0.f, v0 = 0.f, v1 = 0.f, v2 = 0.f;
    float d00 = 0.f, d01 = 0.f, d02 = 0.f,
          d10 = 0.f, d11 = 0.f, d12 = 0.f,
          d20 = 0.f, d21 = 0.f, d22 = 0.f;

#define EDGE_ACC(X, Y, Z, P)                                                  \
    do {                                                                      \
        const float ra = (P)[0], rv = (P)[32], rd = (P)[64];                  \
        accA += ra;                                                           \
        v0 += rv * (X); v1 += rv * (Y); v2 += rv * (Z);                       \
        const float t0 = rd * (X), t1 = rd * (Y), t2 = rd * (Z);              \
        d00 += t0 * (X); d01 += t0 * (Y); d02 += t0 * (Z);                    \
        d10 += t1 * (X); d11 += t1 * (Y); d12 += t1 * (Z);                    \
        d20 += t2 * (X); d21 += t2 * (Y); d22 += t2 * (Z);                    \
    } while (0)

    int i = 0;
    for (; i + 1 < minl; i += 2) {            // no predication, x2 unroll
        float x0, y0, z0, x1, y1, z1;
        const float *p0, *p1;
        if (P16) {
            const float4 qa = ((const float4*)epsv)[s0 + i];
            const float4 qb = ((const float4*)epsv)[s0 + i + 1];
            x0 = qa.x; y0 = qa.y; z0 = qa.z;
            x1 = qb.x; y1 = qb.y; z1 = qb.z;
            p0 = (const float*)(tabA + __float_as_int(qa.w));
            p1 = (const float*)(tabA + __float_as_int(qb.w));
        } else {
            const uint2 qa = ((const uint2*)epsv)[s0 + i];
            const uint2 qb = ((const uint2*)epsv)[s0 + i + 1];
            x0 = __half2float(__ushort_as_half((unsigned short)(qa.x & 0xffff)));
            y0 = __half2float(__ushort_as_half((unsigned short)(qa.x >> 16)));
            z0 = __half2float(__ushort_as_half((unsigned short)(qa.y & 0xffff)));
            x1 = __half2float(__ushort_as_half((unsigned short)(qb.x & 0xffff)));
            y1 = __half2float(__ushort_as_half((unsigned short)(qb.x >> 16)));
            z1 = __half2float(__ushort_as_half((unsigned short)(qb.y & 0xffff)));
            p0 = (const float*)(tabA + (int)(qa.y >> 16) * 384);
            p1 = (const float*)(tabA + (int)(qb.y >> 16) * 384);
        }
        EDGE_ACC(x0, y0, z0, p0);
        EDGE_ACC(x1, y1, z1, p1);
    }
    for (; i < maxl; i++) {                   // tail: predicated per half
        if (i < mylen) {
            float x, y, z;
            const float* p;
            if (P16) {
                const float4 q = ((const float4*)epsv)[s0 + i];
                x = q.x; y = q.y; z = q.z;
                p = (const float*)(tabA + __float_as_int(q.w));
            } else {
                const uint2 q = ((const uint2*)epsv)[s0 + i];
                x = __half2float(__ushort_as_half((unsigned short)(q.x & 0xffff)));
                y = __half2float(__ushort_as_half((unsigned short)(q.x >> 16)));
                z = __half2float(__ushort_as_half((unsigned short)(q.y & 0xffff)));
                p = (const float*)(tabA + (int)(q.y >> 16) * 384);
            }
            EDGE_ACC(x, y, z, p);
        }
    }
#undef EDGE_ACC

    if (myn >= N) return;
    const size_t baseV = (size_t)N * 32;
    const size_t baseD = (size_t)N * 128;
    stf(out, (size_t)myn * 32 + a, accA, f32);
    const size_t vb = baseV + (size_t)myn * 96 + a * 3;
    stf(out, vb + 0, v0, f32);
    stf(out, vb + 1, v1, f32);
    stf(out, vb + 2, v2, f32);
    const size_t db = baseD + (size_t)myn * 288 + a * 9;
    stf(out, db + 0, d00, f32);
    stf(out, db + 1, d01, f32);
    stf(out, db + 2, d02, f32);
    stf(out, db + 3, d10, f32);
    stf(out, db + 4, d11, f32);
    stf(out, db + 5, d12, f32);
    stf(out, db + 6, d20, f32);
    stf(out, db + 7, d21, f32);
    stf(out, db + 8, d22, f32);
}

// --- fallback CSR (global atomics) + perm-based nodes ----------------------
__global__ void k_rank_g(const int* __restrict__ src, int* __restrict__ counts,
                         int* __restrict__ rank, int E) {
    int e = blockIdx.x * blockDim.x + threadIdx.x;
    if (e < E) rank[e] = atomicAdd(&counts[src[e]], 1);
}
__global__ void k_scan_g(const int* __restrict__ counts, int* __restrict__ rowstart,
                         int N, int E) {
    __shared__ int part[1024];
    const int t = threadIdx.x;
    const int CH = (N + 1023) / 1024;
    const int lo = t * CH;
    const int hi = min(lo + CH, N);
    int s = 0;
    for (int i = lo; i < hi; i++) s += counts[i];
    part[t] = s;
    __syncthreads();
    for (int off = 1; off < 1024; off <<= 1) {
        int v = part[t];
        int w = (t >= off) ? part[t - off] : 0;
        __syncthreads();
        part[t] = v + w;
        __syncthreads();
    }
    int run = (t == 0) ? 0 : part[t - 1];
    for (int i = lo; i < hi; i++) { rowstart[i] = run; run += counts[i]; }
    if (t == 0) rowstart[N] = E;
}
__global__ void k_place_g(const int* __restrict__ src, const int* __restrict__ rank,
                          const int* __restrict__ rowstart,
                          int* __restrict__ perm, int E) {
    int e = blockIdx.x * blockDim.x + threadIdx.x;
    if (e < E) perm[rowstart[src[e]] + rank[e]] = e;
}
__global__ void __launch_bounds__(256) k_nodes_fb(
    const int* __restrict__ perm, const void* __restrict__ r_ij,
    const int* __restrict__ rowstart, const float* __restrict__ tabI,
    const int* __restrict__ flag, void* __restrict__ out, int N) {
    const int wave = threadIdx.x >> 6;
    const int lane = threadIdx.x & 63;
    const int n = blockIdx.x * 4 + wave;
    if (n >= N) return;
    const int a = lane & 31;
    const bool hi = (lane >> 5) != 0;
    const bool f32 = flag[0] != 0;
    const int s0 = rowstart[n], s1 = rowstart[n + 1];
    float accR = 0.f, acc1 = 0.f, acc2 = 0.f, acc3 = 0.f,
          acc4 = 0.f, acc5 = 0.f, acc6 = 0.f;
    for (int idx = s0; idx < s1; idx++) {
        const int e = perm[idx];
        const float x0 = ldf(r_ij, 3 * e + 0, f32);
        const float y0 = ldf(r_ij, 3 * e + 1, f32);
        const float z0 = ldf(r_ij, 3 * e + 2, f32);
        const float d2 = x0 * x0 + y0 * y0 + z0 * z0;
        const float inv = rsqrtf(1.0f + 49.0f * d2);
        const float x = 7.0f * x0 * inv, y = 7.0f * y0 * inv, z = 7.0f * z0 * inv;
        const float u = fminf(sqrtf(d2), DMAX) * ((float)(TSIZE - 1) / DMAX);
        const int b = (int)(u + 0.5f) * 96 + a;
        const float ra = tabI[b], rv = tabI[b + 32], rd = tabI[b + 64];
        const float b1 = (hi ? rd : rv) * (hi ? y : 1.0f);
        const float b2 = rd * (hi ? z : x);
        accR += ra;
        acc1 += b1 * x; acc2 += b1 * y; acc3 += b1 * z;
        acc4 += b2 * x; acc5 += b2 * y; acc6 += b2 * z;
    }
    const size_t baseV = (size_t)N * 32;
    const size_t baseD = (size_t)N * 128;
    if (!hi) {
        stf(out, (size_t)n * 32 + a, accR, f32);
        const size_t vb = baseV + (size_t)n * 96 + a * 3;
        stf(out, vb + 0, acc1, f32);
        stf(out, vb + 1, acc2, f32);
        stf(out, vb + 2, acc3, f32);
        const size_t db = baseD + (size_t)n * 288 + a * 9;
        stf(out, db + 0, acc4, f32);
        stf(out, db + 1, acc5, f32);
        stf(out, db + 2, acc6, f32);
    } else {
        const size_t db = baseD + (size_t)n * 288 + a * 9;
        stf(out, db + 3, acc1, f32);
        stf(out, db + 4, acc2, f32);
        stf(out, db + 5, acc3, f32);
        stf(out, db + 6, acc4, f32);
        stf(out, db + 7, acc5, f32);
        stf(out, db + 8, acc6, f32);
    }
}

extern "C" void kernel_launch(void* const* d_in, const int* in_sizes, int n_in,
                              void* d_out, int out_size, void* d_ws, size_t ws_size,
                              hipStream_t stream) {
    const void* r_ij     = d_in[0];
    const void* w_rad    = d_in[1];
    const void* b_rad    = d_in[2];
    const void* w_direct = d_in[3];
    const void* w1       = d_in[4];
    const void* b1       = d_in[5];
    const void* w2       = d_in[6];
    const void* b2       = d_in[7];
    const void* w3       = d_in[8];
    const void* b3       = d_in[9];
    const void* w_v      = d_in[10];
    const void* w_d      = d_in[11];
    const int* edges_src = (const int*)d_in[12];

    const int E = in_sizes[12];
    const int N = out_size / 416;   // 32 + 96 + 288 per node
    const int chunk = (E + HB - 1) / HB;
    const int ntiles = (N + TILE - 1) / TILE;
    const int NB = (N + 63) / 64;

    const size_t cntBytes  = (size_t)ntiles * HB * TILE * 2;
    const size_t tailBytes = ((size_t)W_TOT + 4) * 4 + (size_t)TSIZE * 96 * 4
                           + cntBytes + ((size_t)N + NB + N + 1) * 4;
    const bool p16 = ws_size >= (size_t)E * 16 + tailBytes + 64;
    const bool p8  = !p16 && ws_size >= (size_t)E * 8 + tailBytes + 64;

    char* w = (char*)d_ws;
    if (p16 || p8) {
        const size_t slot = (size_t)E * (p16 ? 16 : 8);
        void* eps     = (void*)w;
        float* wcat   = (float*)(w + slot);
        int* flag     = (int*)(wcat + W_TOT);
        float* tabI   = (float*)(flag + 4);
        unsigned short* cnt = (unsigned short*)(tabI + (size_t)TSIZE * 96);
        int* tot      = (int*)((char*)cnt + cntBytes);
        int* coarse   = tot + N;              // NB entries
        int* rowstart = coarse + NB;          // N+1

        const int nodeBlocks = (N + 2 * NPB - 1) / (2 * NPB);
        k_prep<<<12, 256, 0, stream>>>(
            r_ij, w_rad, b_rad, w_direct, w1, b1, w2, b2, w3, b3, w_v, w_d,
            wcat, flag, nullptr, N);
        k_table<<<TSIZE / EPB, 64 * EPB, 0, stream>>>(wcat, tabI);
        k_hist<<<HB * ntiles, 256, 0, stream>>>(edges_src, E, chunk, cnt, N);
        k_colscan<<<NB, 64, 0, stream>>>(cnt, tot, coarse, N);
        k_scan2<<<NB, 64, 0, stream>>>(tot, coarse, rowstart, N);
        if (p16) {
            k_place<true><<<HB * ntiles, 256, 0, stream>>>(
                edges_src, E, chunk, cnt, rowstart, r_ij, flag, eps, N);
            k_nodes2<true><<<nodeBlocks, 64 * NPB, 0, stream>>>(
                eps, rowstart, tabI, flag, d_out, N);
        } else {
            k_place<false><<<HB * ntiles, 256, 0, stream>>>(
                edges_src, E, chunk, cnt, rowstart, r_ij, flag, eps, N);
            k_nodes2<false><<<nodeBlocks, 64 * NPB, 0, stream>>>(
                eps, rowstart, tabI, flag, d_out, N);
        }
    } else {
        // fallback: global-atomic rank path, perm-indexed nodes
        int* perm     = (int*)w;              // E
        float* wcat   = (float*)(w + (size_t)E * 4);
        int* flag     = (int*)(wcat + W_TOT);
        float* tabI   = (float*)(flag + 4);
        int* counts   = (int*)(tabI + (size_t)TSIZE * 96);
        int* rowstart = counts + N;           // N+1
        int* rank     = rowstart + N + 1;     // E

        k_prep<<<12 + (N + 255) / 256, 256, 0, stream>>>(
            r_ij, w_rad, b_rad, w_direct, w1, b1, w2, b2, w3, b3, w_v, w_d,
            wcat, flag, counts, N);
        k_table<<<TSIZE / EPB, 64 * EPB, 0, stream>>>(wcat, tabI);
        k_rank_g<<<(E + 255) / 256, 256, 0, stream>>>(edges_src, counts, rank, E);
        k_scan_g<<<1, 1024, 0, stream>>>(counts, rowstart, N, E);
        k_place_g<<<(E + 255) / 256, 256, 0, stream>>>(edges_src, rank, rowstart,
                                                       perm, E);
        k_nodes_fb<<<(N + 3) / 4, 256, 0, stream>>>(
            perm, r_ij, rowstart, tabI, flag, d_out, N);
    }
}